// Round 4
// baseline (321.982 us; speedup 1.0000x reference)
//
#include <hip/hip_runtime.h>

typedef _Float16 f16x8 __attribute__((ext_vector_type(8)));
typedef float    f32x4 __attribute__((ext_vector_type(4)));

#define NSTEP 512
#define CHUNK 4
#define NCHUNK (NSTEP / CHUNK)
#define LOG2E     1.4426950408889634f
#define TWOLOG2E  2.8853900817779268f

__device__ __forceinline__ float exp2_(float v) { return __builtin_amdgcn_exp2f(v); }

// Exp2-domain 7-trans LSTM activation. Gates arrive PRE-SCALED from the MFMA:
// gi,gf,go = -log2(e)*(preact), gg = +2log2(e)*(preact).
__device__ __forceinline__ float lstm_act_(float gi, float gf, float gg, float go, float& c) {
    float eg = exp2_(gg);
    float ei = exp2_(gi);
    float ef = exp2_(gf);
    float eo = exp2_(go);
    float X  = (eg + 1.0f) * (1.0f + ei);
    float Y  = 1.0f + ef;
    float r  = __builtin_amdgcn_rcpf(X * Y);
    c = fmaf(r * X, c, (eg - 1.0f) * (r * Y));
    float ec = exp2_(fminf(c * TWOLOG2E, 30.0f));
    float r2 = __builtin_amdgcn_rcpf((ec + 1.0f) * (1.0f + eo));
    return (ec - 1.0f) * r2;
}
__device__ __forceinline__ float sig_(float v) {
    return __builtin_amdgcn_rcpf(1.0f + exp2_(-v * LOG2E));
}
__device__ __forceinline__ float tanh_(float v) {
    return 1.0f - 2.0f * __builtin_amdgcn_rcpf(exp2_(v * TWOLOG2E) + 1.0f);
}

// lgkmcnt-only barrier: does NOT drain vmcnt, so global x-prefetch loads float
// across the whole chunk. asm "memory" fences pin LDS ops on both sides.
__device__ __forceinline__ void bar_() {
    asm volatile("s_waitcnt lgkmcnt(0)" ::: "memory");
    __builtin_amdgcn_s_barrier();
    asm volatile("" ::: "memory");
}

// R19: 4 waves x 4 tiles (256 thr, 1 wave/SIMD). Under lockstep barriers,
// 2 waves/SIMD serialize on the trans/VALU pipes (no overlap) -- 1 wave/SIMD
// runs the same per-CU act work at half the per-SIMD serialization, with the
// 4 cells' ILP pipelining the trans unit. LDS reads/step: 8 b128/CU (was 16),
// barrier width 4. CHUNK=4 keeps reg-resident ax at 64 VGPR. All R18 tricks
// retained (exp2-domain weights, reg ax seed, vmcnt-floating prefetch,
// Pe dbuf written at step 0 of each chunk).
__global__ __launch_bounds__(256, 1) void lstm_mfma16_kernel(
    const float* __restrict__ x,     const float* __restrict__ Wemb,
    const float* __restrict__ Wih1,  const float* __restrict__ Whh1,
    const float* __restrict__ b1,    const float* __restrict__ Wih2,
    const float* __restrict__ b2,    const float* __restrict__ Wout,
    const float* __restrict__ bout,  float* __restrict__ out)
{
    __shared__ __align__(16) _Float16 P[2][2][4][16][8];       // 4096 B  h-panel dbuf
    __shared__ __align__(16) _Float16 Pe[2][CHUNK][4][16][8];  // 8192 B  emb panel dbuf
    __shared__ __align__(16) float h2tmp[16 * 64];             // 4096 B
    __shared__ __align__(16) float h2s[256 * 16];              // 16384 B
    __shared__ float part[16 * 16 * 2];                        // 2048 B

    const int t   = threadIdx.x;
    const int l   = t & 63;
    const int w   = t >> 6;      // wave 0..3; owns tiles 4w..4w+3
    const int m   = l & 15;      // A-row / B col (batch) / D col
    const int q   = l >> 4;      // quad
    const int b0  = blockIdx.x * 16;

    // ---- weight fragments for 4 tiles (exp2-domain scaled) -----------------
    f16x8 whh[4][2], whE[4];
    f32x4 bias4[4];
    #pragma unroll
    for (int tt = 0; tt < 4; ++tt) {
        const int tau = 4 * w + tt;
        const int g = m & 3;
        const float sc = (g == 2) ? TWOLOG2E : -LOG2E;
        const int n = g * 64 + 4 * tau + (m >> 2);
        #pragma unroll
        for (int c = 0; c < 2; ++c)
            #pragma unroll
            for (int jj = 0; jj < 8; ++jj)
                whh[tt][c][jj] = (_Float16)(Whh1[n * 64 + c * 32 + (q << 3) + jj] * sc);
        #pragma unroll
        for (int jj = 0; jj < 8; ++jj) {
            int k = (q << 3) + jj;
            whE[tt][jj] = (_Float16)((k < 20) ? Wih1[n * 20 + k] * sc : 0.0f);
        }
        #pragma unroll
        for (int r = 0; r < 4; ++r) {
            float scr = (r == 2) ? TWOLOG2E : -LOG2E;
            bias4[tt][r] = b1[r * 64 + 4 * tau + q] * scr;
        }
    }

    // lane's act cells: unit 16w + 4tt + q, batch m
    _Float16* hw[4];
    #pragma unroll
    for (int tt = 0; tt < 4; ++tt) {
        const int myu = 16 * w + 4 * tt + q;
        hw[tt] = &P[0][myu >> 5][(myu >> 3) & 3][m][myu & 7];
    }
    const _Float16* rb = &P[0][0][q][m][0];   // B-fragment base (lane-linear)
    // parity stride = one P buffer = 1024 f16; Pe buffer stride = 2048 f16

    // ---- emb writer slots: v = t + 256k, k=0..4 (1280 = 5*256, all valid) --
    // pair = v/20 -> (batch = pair&15, s = pair>>4), dim d = v%20
    const float* xp[5]; _Float16* pe[5];
    float we0[5], we1[5];
    float2 xv[5];
    #pragma unroll
    for (int k = 0; k < 5; ++k) {
        int v  = t + 256 * k;
        int d  = v % 20, pr = v / 20;
        int bb = pr & 15, s = pr >> 4;
        we0[k] = Wemb[2 * d];
        we1[k] = Wemb[2 * d + 1];
        pe[k]  = &Pe[0][s][d >> 3][bb][d & 7];
        xp[k]  = x + (size_t)(b0 + bb) * (2 * NSTEP) + 2 * s;
        xv[k]  = *(const float2*)xp[k];                    // chunk-0 data
    }

    // ---- zero P (h(-1)=0) and all of Pe (pads d=20..31 stay 0 forever) -----
    #pragma unroll
    for (int k = 0; k < 8; ++k) ((_Float16*)P)[t + 256 * k] = (_Float16)0.0f;
    {
        _Float16* pz = (_Float16*)Pe;
        #pragma unroll
        for (int k = 0; k < 16; ++k) pz[t + 256 * k] = (_Float16)0.0f;
    }
    __syncthreads();
    // fill Pe[0] with chunk 0's panel, then prefetch chunk 1's x
    #pragma unroll
    for (int k = 0; k < 5; ++k)
        pe[k][0] = (_Float16)fmaxf(fmaf(xv[k].x, we0[k], xv[k].y * we1[k]), 0.0f);
    #pragma unroll
    for (int k = 0; k < 5; ++k) { xp[k] += 2 * CHUNK; xv[k] = *(const float2*)xp[k]; }
    __syncthreads();

    // ---- main recurrence: 128 chunks x 4 steps ------------------------------
    float cst[4] = {0.f, 0.f, 0.f, 0.f};
    for (int ch = 0; ch < NCHUNK; ++ch) {
        const int pb = ch & 1;                           // Pe read buffer
        const _Float16* peR = (const _Float16*)Pe + pb * 2048;

        // phase B: ax[tile][j] = Wih*e(t) + b, in registers (lane == consumer)
        f32x4 ax[4][CHUNK];
        #pragma unroll
        for (int j = 0; j < CHUNK; ++j) {
            f16x8 fe = *(const f16x8*)(peR + j * 512 + q * 128 + m * 8);
            #pragma unroll
            for (int tt = 0; tt < 4; ++tt)
                ax[tt][j] = __builtin_amdgcn_mfma_f32_16x16x32_f16(whE[tt], fe, bias4[tt], 0, 0, 0);
        }

        // phase C: 4 recurrence steps, parity static per unrolled slot
        #pragma unroll
        for (int j = 0; j < CHUNK; ++j) {
            const int pr = j & 1;
            f16x8 f0 = *(const f16x8*)(rb + pr * 1024);
            f16x8 f1 = *(const f16x8*)(rb + pr * 1024 + 512);
            f32x4 a[4];
            #pragma unroll
            for (int tt = 0; tt < 4; ++tt)
                a[tt] = __builtin_amdgcn_mfma_f32_16x16x32_f16(whh[tt][0], f0, ax[tt][j], 0, 0, 0);
            #pragma unroll
            for (int tt = 0; tt < 4; ++tt)
                a[tt] = __builtin_amdgcn_mfma_f32_16x16x32_f16(whh[tt][1], f1, a[tt], 0, 0, 0);
            #pragma unroll
            for (int tt = 0; tt < 4; ++tt) {
                float hv = lstm_act_(a[tt][0], a[tt][1], a[tt][2], a[tt][3], cst[tt]);
                hw[tt][(pr ^ 1) * 1024] = (_Float16)hv;
            }
            if (j == 0) {
                // write NEXT chunk's emb panel (buffer pb^1) from xv regs;
                // at ch==NCHUNK-1 this writes stale data to a dead buffer.
                #pragma unroll
                for (int k = 0; k < 5; ++k)
                    pe[k][(pb ^ 1) * 2048] =
                        (_Float16)fmaxf(fmaf(xv[k].x, we0[k], xv[k].y * we1[k]), 0.0f);
                if (ch + 2 < NCHUNK) {
                    #pragma unroll
                    for (int k = 0; k < 5; ++k) { xp[k] += 2 * CHUNK; xv[k] = *(const float2*)xp[k]; }
                }
            }
            bar_();
        }
    }
    // final h(511) in P[0]

    // ---- epilogue: h64 to fp32 (1024 values, four per thread) --------------
    #pragma unroll
    for (int r = 0; r < 4; ++r) {
        int tt = t + 256 * r;
        int b = tt >> 6, k = tt & 63;
        h2tmp[tt] = (float)P[0][k >> 5][(k >> 3) & 3][b][k & 7];
    }
    __syncthreads();

    // ---- LSTM2 (single step, h=c=0 -> f-gate irrelevant) -------------------
    {
        const int u = t;                            // 256 units, 16 batches each
        float acci[16], accg[16], acco[16];
        float bi2 = b2[u], bg2 = b2[512 + u], bo2 = b2[768 + u];
        #pragma unroll
        for (int b = 0; b < 16; ++b) { acci[b] = bi2; accg[b] = bg2; acco[b] = bo2; }
        for (int k4 = 0; k4 < 64; k4 += 4) {
            float4 wi = *(const float4*)&Wih2[(size_t)u * 64 + k4];
            float4 wg = *(const float4*)&Wih2[(size_t)(512 + u) * 64 + k4];
            float4 wo = *(const float4*)&Wih2[(size_t)(768 + u) * 64 + k4];
            #pragma unroll
            for (int b = 0; b < 16; ++b) {
                float4 hb = *(const float4*)&h2tmp[b * 64 + k4];
                acci[b] += wi.x * hb.x + wi.y * hb.y + wi.z * hb.z + wi.w * hb.w;
                accg[b] += wg.x * hb.x + wg.y * hb.y + wg.z * hb.z + wg.w * hb.w;
                acco[b] += wo.x * hb.x + wo.y * hb.y + wo.z * hb.z + wo.w * hb.w;
            }
        }
        #pragma unroll
        for (int b = 0; b < 16; ++b) {
            float c2 = sig_(acci[b]) * tanh_(accg[b]);
            h2s[u * 16 + b] = sig_(acco[b]) * tanh_(c2);
        }
    }
    __syncthreads();

    // ---- output projection --------------------------------------------------
    {
        int b = t & 15, grp = t >> 4;            // 16 groups x 16 units
        float p0 = 0.f, p1 = 0.f;
        #pragma unroll
        for (int uu = grp * 16; uu < grp * 16 + 16; ++uu) {
            float hvv = h2s[uu * 16 + b];
            p0 += hvv * Wout[uu];
            p1 += hvv * Wout[256 + uu];
        }
        part[(grp * 16 + b) * 2 + 0] = p0;
        part[(grp * 16 + b) * 2 + 1] = p1;
    }
    __syncthreads();
    if (t < 32) {
        int b = t >> 1, o = t & 1;
        float s0 = bout[o];
        for (int grp = 0; grp < 16; ++grp) s0 += part[(grp * 16 + b) * 2 + o];
        out[(size_t)(b0 + b) * 2 + o] = s0;
    }
}

extern "C" void kernel_launch(void* const* d_in, const int* in_sizes, int n_in,
                              void* d_out, int out_size, void* d_ws, size_t ws_size,
                              hipStream_t stream) {
    const float* x    = (const float*)d_in[0];
    const float* Wemb = (const float*)d_in[1];
    const float* Wih1 = (const float*)d_in[2];
    const float* Whh1 = (const float*)d_in[3];
    const float* b1   = (const float*)d_in[4];
    const float* Wih2 = (const float*)d_in[5];
    // d_in[6] = Whh2: unused (h=c=0 at LSTM2's single step)
    const float* b2   = (const float*)d_in[7];
    const float* Wout = (const float*)d_in[8];
    const float* bout = (const float*)d_in[9];
    float* out = (float*)d_out;

    lstm_mfma16_kernel<<<256, 256, 0, stream>>>(
        x, Wemb, Wih1, Whh1, b1, Wih2, b2, Wout, bout, out);
}